// Round 4
// baseline (599.055 us; speedup 1.0000x reference)
//
#include <hip/hip_runtime.h>

typedef unsigned short u16;
typedef __bf16 bf16x8 __attribute__((ext_vector_type(8)));
typedef float f32x4 __attribute__((ext_vector_type(4)));

#define B_   2
#define S_   2048
#define HID_ 2048
#define H_   16
#define KV_  4
#define D_   128

__device__ __forceinline__ u16 f2b(float f) {
  unsigned u = __float_as_uint(f);
  return (u16)((u + 0x7fffu + ((u >> 16) & 1u)) >> 16);  // RNE
}
__device__ __forceinline__ float b2f(u16 h) {
  return __uint_as_float(((unsigned)h) << 16);
}
__device__ __forceinline__ unsigned pk2(float a, float b) {
  return ((unsigned)f2b(b) << 16) | (unsigned)f2b(a);  // a low 16, b high 16
}
__device__ __forceinline__ void cstore(float* p, float v) { *p = v; }
__device__ __forceinline__ void cstore(u16* p, float v)   { *p = f2b(v); }

// async global->LDS, 16B per lane; LDS dest = wave-uniform base + lane*16
__device__ __forceinline__ void gl_lds16(const u16* g, u16* l) {
  __builtin_amdgcn_global_load_lds(
      (const __attribute__((address_space(1))) unsigned int*)g,
      (__attribute__((address_space(3))) unsigned int*)l, 16, 0, 0);
}

// ---------------------------------------------------------------- cast x -> bf16
__global__ __launch_bounds__(256)
void cast_f2b_kernel(const float* __restrict__ in, u16* __restrict__ out, int n) {
  int i = (blockIdx.x * 256 + threadIdx.x) * 4;
  if (i + 3 < n) {
    float4 v = *(const float4*)(in + i);
    uint2 r = make_uint2(pk2(v.x, v.y), pk2(v.z, v.w));
    *(uint2*)(out + i) = r;
  }
}

// ------------------------------------------- W (R x C) fp32 -> Wt (C x R) bf16
__global__ __launch_bounds__(256)
void transpose_w_kernel(const float* __restrict__ in, u16* __restrict__ out,
                        int R, int Cc) {
  __shared__ u16 t[32][33];
  const int tx = threadIdx.x, ty = threadIdx.y;
  const int c0 = blockIdx.x * 32, r0 = blockIdx.y * 32;
#pragma unroll
  for (int i = 0; i < 4; i++)
    t[ty + i * 8][tx] = f2b(in[(size_t)(r0 + ty + i * 8) * Cc + c0 + tx]);
  __syncthreads();
#pragma unroll
  for (int i = 0; i < 4; i++)
    out[(size_t)(c0 + ty + i * 8) * R + r0 + tx] = t[tx][ty + i * 8];
}

// ------------------- v slice of kvraw (tok, TS) -> Vt (B,KV,D,S) bf16
__global__ __launch_bounds__(256)
void transpose_v_kernel(const u16* __restrict__ in, u16* __restrict__ out,
                        int tokstride) {
  __shared__ u16 t[32][33];
  const int tx = threadIdx.x, ty = threadIdx.y;
  const int s0 = blockIdx.x * 32, d0 = blockIdx.y * 32;
  const int z = blockIdx.z, b = z >> 2, kv = z & 3;
#pragma unroll
  for (int i = 0; i < 4; i++)
    t[ty + i * 8][tx] =
        in[(size_t)(b * S_ + s0 + ty + i * 8) * tokstride + kv * D_ + d0 + tx];
  __syncthreads();
#pragma unroll
  for (int i = 0; i < 4; i++)
    out[((size_t)(b * KV_ + kv) * D_ + d0 + ty + i * 8) * S_ + s0 + tx] =
        t[tx][ty + i * 8];
}

// --------------------------------- NT GEMM: A (M,K) bf16, Bt (N,K) bf16, C (M,N)
// m97 structure: 128x128 tile, BK=32, global_load_lds width=16, unpadded LDS.
template <typename CT>
__global__ __launch_bounds__(256)
void gemm_nt(const u16* __restrict__ A, const u16* __restrict__ Bt,
             CT* __restrict__ C, int Md, int Nd, int Kd) {
  __shared__ u16 As[128 * 32];
  __shared__ u16 Bs[128 * 32];
  const int tid = threadIdx.x;
  const int lane = tid & 63;
  const int wave = tid >> 6;
  const int wm = wave >> 1, wn = wave & 1;
  const int li = lane & 15, quad = lane >> 4;
  const int m0 = blockIdx.y * 128;
  const int n0 = blockIdx.x * 128;

  f32x4 acc[4][4];
#pragma unroll
  for (int i = 0; i < 4; i++)
#pragma unroll
    for (int j = 0; j < 4; j++) acc[i][j] = (f32x4){0.f, 0.f, 0.f, 0.f};

  const int srow = wave * 32 + (lane >> 2);
  const int scol = (lane & 3) * 8;
  const u16* Ag0 = A + (size_t)(m0 + srow) * Kd + scol;
  const u16* Ag1 = Ag0 + (size_t)16 * Kd;
  const u16* Bg0 = Bt + (size_t)(n0 + srow) * Kd + scol;
  const u16* Bg1 = Bg0 + (size_t)16 * Kd;
  u16* Al0 = &As[(wave * 32) * 32];
  u16* Al1 = &As[(wave * 32 + 16) * 32];
  u16* Bl0 = &Bs[(wave * 32) * 32];
  u16* Bl1 = &Bs[(wave * 32 + 16) * 32];

  for (int k0 = 0; k0 < Kd; k0 += 32) {
    __syncthreads();
    gl_lds16(Ag0 + k0, Al0);
    gl_lds16(Ag1 + k0, Al1);
    gl_lds16(Bg0 + k0, Bl0);
    gl_lds16(Bg1 + k0, Bl1);
    __syncthreads();
    bf16x8 af[4], bfr[4];
#pragma unroll
    for (int mt = 0; mt < 4; mt++)
      af[mt] = *(const bf16x8*)&As[(wm * 64 + mt * 16 + li) * 32 + quad * 8];
#pragma unroll
    for (int nt = 0; nt < 4; nt++)
      bfr[nt] = *(const bf16x8*)&Bs[(wn * 64 + nt * 16 + li) * 32 + quad * 8];
#pragma unroll
    for (int mt = 0; mt < 4; mt++)
#pragma unroll
      for (int nt = 0; nt < 4; nt++)
        acc[mt][nt] = __builtin_amdgcn_mfma_f32_16x16x32_bf16(
            af[mt], bfr[nt], acc[mt][nt], 0, 0, 0);
  }
#pragma unroll
  for (int mt = 0; mt < 4; mt++) {
    const int row = m0 + wm * 64 + mt * 16 + quad * 4;
#pragma unroll
    for (int nt = 0; nt < 4; nt++) {
      const int col = n0 + wn * 64 + nt * 16 + li;
#pragma unroll
      for (int r = 0; r < 4; r++)
        cstore(&C[(size_t)(row + r) * Nd + col], acc[mt][nt][r]);
    }
  }
}

// ------------------------ fused RMSNorm (w+1) + RoPE (+ optional score scale)
__global__ __launch_bounds__(256)
void rmsrope_kernel(const u16* __restrict__ in, const float* __restrict__ w,
                    u16* __restrict__ out, int n_heads, int tok_stride,
                    int head_stride, float scale) {
  const int warp = (blockIdx.x << 2) + (threadIdx.x >> 6);
  const int lane = threadIdx.x & 63;
  const int h = warp % n_heads;
  const int tok = warp / n_heads;
  const int s = tok & (S_ - 1);
  const int b = tok >> 11;
  const u16* src = in + (size_t)tok * tok_stride + (size_t)h * head_stride;
  float x1 = b2f(src[lane]);
  float x2 = b2f(src[lane + 64]);
  float ss = x1 * x1 + x2 * x2;
#pragma unroll
  for (int off = 1; off < 64; off <<= 1) ss += __shfl_xor(ss, off);
  const float inv = rsqrtf(ss * (1.0f / 128.0f) + 1e-6f) * scale;
  x1 *= inv * (w[lane] + 1.0f);
  x2 *= inv * (w[lane + 64] + 1.0f);
  const float invf = exp2f((float)lane * (-19.931568569324174f / 64.0f));
  const float ang = (float)s * invf;
  float sn, c;
  sincosf(ang, &sn, &c);
  const size_t ob = (((size_t)b * n_heads + h) * S_ + s) * D_;
  out[ob + lane]      = f2b(x1 * c - x2 * sn);
  out[ob + lane + 64] = f2b(x2 * c + x1 * sn);
}

// --------------------------- flash attention (transposed-S), GQA causal
// Pair-balanced: block handles q-tiles qt0=x and qt1=31-x (64 rows each) over
// one shared key loop -> every block ~33 compute-tile-equivalents.
// h2=0 -> qt0 rows, h2=1 -> qt1 rows. K/V prefetched into VGPRs (SW pipeline).
// Gate (sigmoid from qraw) fused into epilogue; writes Ag directly.
#define KSTR 136
#define VSTR 72
#define PSTR 72
#define OSTR 136
__global__ __launch_bounds__(256)
void attn_kernel(const u16* __restrict__ Q, const u16* __restrict__ Kr,
                 const u16* __restrict__ Vt, const u16* __restrict__ qraw,
                 u16* __restrict__ Ag) {
  __shared__ u16 lds[27136];               // 54,272 B
  u16* Ks = lds;                           // 64 x 136
  u16* Vs = lds + 64 * KSTR;               // 128 x 72
  u16* Ps = lds + 64 * KSTR + 128 * VSTR;  // 4 waves x 32 x 72
  u16* Osm = lds;                          // aliases Ks+Vs after loop

  const int tid = threadIdx.x;
  const int lane = tid & 63;
  const int wave = tid >> 6;
  const int li = lane & 15, quad = lane >> 4;

  const int bh = blockIdx.y;
  const int b = bh >> 4, h = bh & 15;
  const int kv = h >> 2;
  const int qt0 = blockIdx.x;        // light q-tile
  const int qt1 = 31 - blockIdx.x;   // heavy q-tile

  const u16* Qb = Q + (size_t)bh * S_ * D_;
  const u16* Kb = Kr + ((size_t)b * KV_ + kv) * S_ * D_;
  const u16* Vb = Vt + ((size_t)b * KV_ + kv) * D_ * S_;

  bf16x8 qf[2][4];  // B-operand of Q^T
#pragma unroll
  for (int h2 = 0; h2 < 2; h2++) {
    const int qrow = (h2 ? qt1 : qt0) * 64 + wave * 16 + li;
#pragma unroll
    for (int dc = 0; dc < 4; dc++)
      qf[h2][dc] = *(const bf16x8*)(Qb + (size_t)qrow * D_ + dc * 32 + quad * 8);
  }

  float m_s[2] = {-1e30f, -1e30f}, l_s[2] = {0.f, 0.f};
  f32x4 oacc[2][8];
#pragma unroll
  for (int h2 = 0; h2 < 2; h2++)
#pragma unroll
    for (int i = 0; i < 8; i++) oacc[h2][i] = (f32x4){0.f, 0.f, 0.f, 0.f};

  const int ntile = qt1 + 1;
  const int kr = tid >> 2, kc = (tid & 3) * 32;
  const int vr = tid >> 1, vc = (tid & 1) * 32;
  u16* Pw = Ps + wave * 32 * PSTR;

  uint4 kp[4], vp[4];
  auto loadkv = [&](int j0) {
    const u16* ksrc = Kb + (size_t)(j0 + kr) * D_ + kc;
    kp[0] = *(const uint4*)(ksrc);
    kp[1] = *(const uint4*)(ksrc + 8);
    kp[2] = *(const uint4*)(ksrc + 16);
    kp[3] = *(const uint4*)(ksrc + 24);
    const u16* vsrc = Vb + (size_t)vr * S_ + j0 + vc;
    vp[0] = *(const uint4*)(vsrc);
    vp[1] = *(const uint4*)(vsrc + 8);
    vp[2] = *(const uint4*)(vsrc + 16);
    vp[3] = *(const uint4*)(vsrc + 24);
  };
  loadkv(0);

  for (int jt = 0; jt < ntile; jt++) {
    const bool act0 = (jt <= qt0);  // block-uniform
    __syncthreads();
    {  // commit prefetched K/V to LDS
      u16* kd = &Ks[kr * KSTR + kc];
      *(uint4*)(kd) = kp[0]; *(uint4*)(kd + 8) = kp[1];
      *(uint4*)(kd + 16) = kp[2]; *(uint4*)(kd + 24) = kp[3];
      u16* vd = &Vs[vr * VSTR + vc];
      *(uint4*)(vd) = vp[0]; *(uint4*)(vd + 8) = vp[1];
      *(uint4*)(vd + 16) = vp[2]; *(uint4*)(vd + 24) = vp[3];
    }
    __syncthreads();
    if (jt + 1 < ntile) loadkv((jt + 1) * 64);  // fly during compute

    // S^T = K·Q^T : rows=keys, cols=q
    f32x4 sacc[2][4];
#pragma unroll
    for (int h2 = 0; h2 < 2; h2++)
#pragma unroll
      for (int mt = 0; mt < 4; mt++) sacc[h2][mt] = (f32x4){0.f, 0.f, 0.f, 0.f};
    if (act0) {
#pragma unroll
      for (int mt = 0; mt < 4; mt++)
#pragma unroll
        for (int dc = 0; dc < 4; dc++) {
          bf16x8 kf = *(const bf16x8*)&Ks[(mt * 16 + li) * KSTR + dc * 32 + quad * 8];
          sacc[0][mt] = __builtin_amdgcn_mfma_f32_16x16x32_bf16(kf, qf[0][dc],
                                                                sacc[0][mt], 0, 0, 0);
          sacc[1][mt] = __builtin_amdgcn_mfma_f32_16x16x32_bf16(kf, qf[1][dc],
                                                                sacc[1][mt], 0, 0, 0);
        }
    } else {
#pragma unroll
      for (int mt = 0; mt < 4; mt++)
#pragma unroll
        for (int dc = 0; dc < 4; dc++) {
          bf16x8 kf = *(const bf16x8*)&Ks[(mt * 16 + li) * KSTR + dc * 32 + quad * 8];
          sacc[1][mt] = __builtin_amdgcn_mfma_f32_16x16x32_bf16(kf, qf[1][dc],
                                                                sacc[1][mt], 0, 0, 0);
        }
    }
    // causal mask: only on each h2's diagonal tile (j0 == qt*64)
#pragma unroll
    for (int h2 = 0; h2 < 2; h2++) {
      if (jt == (h2 ? qt1 : qt0)) {
        const int qg = wave * 16 + li;  // q - j0
#pragma unroll
        for (int mt = 0; mt < 4; mt++)
#pragma unroll
          for (int r = 0; r < 4; r++)
            if (mt * 16 + quad * 4 + r > qg) sacc[h2][mt][r] = -1e30f;
      }
    }
    // online softmax (per h2, block-uniform activity)
    float alpha[2];
#pragma unroll
    for (int h2 = 0; h2 < 2; h2++) {
      if (h2 == 0 && !act0) continue;
      float mx = -1e30f;
#pragma unroll
      for (int mt = 0; mt < 4; mt++)
#pragma unroll
        for (int r = 0; r < 4; r++) mx = fmaxf(mx, sacc[h2][mt][r]);
      mx = fmaxf(mx, __shfl_xor(mx, 16));
      mx = fmaxf(mx, __shfl_xor(mx, 32));
      const float mn = fmaxf(m_s[h2], mx);
      alpha[h2] = __expf(m_s[h2] - mn);
      m_s[h2] = mn;
      float rs = 0.f;
#pragma unroll
      for (int mt = 0; mt < 4; mt++)
#pragma unroll
        for (int r = 0; r < 4; r++) {
          float p = __expf(sacc[h2][mt][r] - mn);
          sacc[h2][mt][r] = p;
          rs += p;
        }
      rs += __shfl_xor(rs, 16);
      rs += __shfl_xor(rs, 32);
      l_s[h2] = l_s[h2] * alpha[h2] + rs;
#pragma unroll
      for (int mt = 0; mt < 8; mt++) {
        oacc[h2][mt][0] *= alpha[h2];
        oacc[h2][mt][1] *= alpha[h2];
        oacc[h2][mt][2] *= alpha[h2];
        oacc[h2][mt][3] *= alpha[h2];
      }
      // P^T -> wave-private LDS (rows=q, cols=keys)
#pragma unroll
      for (int mt = 0; mt < 4; mt++) {
        uint2 w2;
        w2.x = pk2(sacc[h2][mt][0], sacc[h2][mt][1]);
        w2.y = pk2(sacc[h2][mt][2], sacc[h2][mt][3]);
        *(uint2*)&Pw[(h2 * 16 + li) * PSTR + mt * 16 + quad * 4] = w2;
      }
    }
    asm volatile("s_waitcnt lgkmcnt(0)" ::: "memory");  // wave-private round trip
    if (act0) {
      bf16x8 pf0[2], pf1[2];
#pragma unroll
      for (int ks = 0; ks < 2; ks++) {
        pf0[ks] = *(const bf16x8*)&Pw[(0 * 16 + li) * PSTR + ks * 32 + quad * 8];
        pf1[ks] = *(const bf16x8*)&Pw[(1 * 16 + li) * PSTR + ks * 32 + quad * 8];
      }
#pragma unroll
      for (int mt = 0; mt < 8; mt++)
#pragma unroll
        for (int ks = 0; ks < 2; ks++) {
          bf16x8 vf = *(const bf16x8*)&Vs[(mt * 16 + li) * VSTR + ks * 32 + quad * 8];
          oacc[0][mt] = __builtin_amdgcn_mfma_f32_16x16x32_bf16(vf, pf0[ks],
                                                                oacc[0][mt], 0, 0, 0);
          oacc[1][mt] = __builtin_amdgcn_mfma_f32_16x16x32_bf16(vf, pf1[ks],
                                                                oacc[1][mt], 0, 0, 0);
        }
    } else {
      bf16x8 pf1[2];
#pragma unroll
      for (int ks = 0; ks < 2; ks++)
        pf1[ks] = *(const bf16x8*)&Pw[(1 * 16 + li) * PSTR + ks * 32 + quad * 8];
#pragma unroll
      for (int mt = 0; mt < 8; mt++)
#pragma unroll
        for (int ks = 0; ks < 2; ks++) {
          bf16x8 vf = *(const bf16x8*)&Vs[(mt * 16 + li) * VSTR + ks * 32 + quad * 8];
          oacc[1][mt] = __builtin_amdgcn_mfma_f32_16x16x32_bf16(vf, pf1[ks],
                                                                oacc[1][mt], 0, 0, 0);
        }
    }
  }

  __syncthreads();  // all waves done with Ks/Vs before Osm alias write
  float linv[2] = {1.f / l_s[0], 1.f / l_s[1]};
#pragma unroll
  for (int h2 = 0; h2 < 2; h2++)
#pragma unroll
    for (int mt = 0; mt < 8; mt++) {
      uint2 w2;
      w2.x = pk2(oacc[h2][mt][0] * linv[h2], oacc[h2][mt][1] * linv[h2]);
      w2.y = pk2(oacc[h2][mt][2] * linv[h2], oacc[h2][mt][3] * linv[h2]);
      *(uint2*)&Osm[(h2 * 64 + wave * 16 + li) * OSTR + mt * 16 + quad * 4] = w2;
    }
  __syncthreads();
  {  // epilogue: gate (sigmoid from qraw) + store Ag (tok, H*D), coalesced
    const int r = tid >> 1, c0 = (tid & 1) * 64;
    const int s = (r < 64) ? (qt0 * 64 + r) : (qt1 * 64 + (r - 64));
    const size_t tok = (size_t)b * S_ + s;
    const u16* gp = qraw + (tok * 16 + h) * 256 + 128 + c0;
    u16* dst = Ag + tok * 2048 + h * 128 + c0;
#pragma unroll
    for (int i = 0; i < 8; i++) {
      uint4 ov = *(const uint4*)&Osm[r * OSTR + c0 + i * 8];
      uint4 gv = *(const uint4*)(gp + i * 8);
      const unsigned* ou = (const unsigned*)&ov;
      const unsigned* gu = (const unsigned*)&gv;
      uint4 res;
      unsigned* ru = (unsigned*)&res;
#pragma unroll
      for (int j = 0; j < 4; j++) {
        float o0 = b2f((u16)(ou[j] & 0xffff)), o1 = b2f((u16)(ou[j] >> 16));
        float g0 = b2f((u16)(gu[j] & 0xffff)), g1 = b2f((u16)(gu[j] >> 16));
        ru[j] = pk2(o0 / (1.f + __expf(-g0)), o1 / (1.f + __expf(-g1)));
      }
      *(uint4*)(dst + i * 8) = res;
    }
  }
}

extern "C" void kernel_launch(void* const* d_in, const int* in_sizes, int n_in,
                              void* d_out, int out_size, void* d_ws,
                              size_t ws_size, hipStream_t stream) {
  const float* x  = (const float*)d_in[0];
  const float* Wq = (const float*)d_in[1];
  const float* Wk = (const float*)d_in[2];
  const float* Wv = (const float*)d_in[3];
  const float* Wo = (const float*)d_in[4];
  const float* qn = (const float*)d_in[5];
  const float* kn = (const float*)d_in[6];
  float* out = (float*)d_out;
  char* ws = (char*)d_ws;

  u16* xb    = (u16*)(ws + 0);          // 16.8 MB  x bf16 (4096x2048)
  u16* Wqt   = (u16*)(ws + 16777216);   // 16.8 MB  Wq^T (4096x2048)
  u16* Wkvt  = (u16*)(ws + 33554432);   //  4.2 MB  [Wk^T; Wv^T] (1024x2048)
  u16* Wot   = (u16*)(ws + 37748736);   //  8.4 MB  Wo^T (2048x2048)
  u16* qraw  = (u16*)(ws + 46137344);   // 33.6 MB  q_raw (4096x4096)
  u16* kvraw = (u16*)(ws + 79691776);   //  8.4 MB  [k|v] (4096x1024)
  u16* Vtb   = (u16*)(ws + 88080384);   //  4.2 MB  V^T (B,KV,D,S)
  u16* Kr    = (u16*)(ws + 92274688);   //  4.2 MB  K roped (B,KV,S,D)
  u16* Ag    = (u16*)(ws + 96468992);   // 16.8 MB  gated attn (4096x2048)
  u16* Qr = xb;  // (B,H,S,D) roped+scaled Q (aliases xb, dead after GEMMs)

  cast_f2b_kernel<<<8192, 256, 0, stream>>>(x, xb, 4096 * 2048);
  transpose_w_kernel<<<dim3(128, 64), dim3(32, 8), 0, stream>>>(Wq, Wqt, 2048, 4096);
  transpose_w_kernel<<<dim3(16, 64), dim3(32, 8), 0, stream>>>(Wk, Wkvt, 2048, 512);
  transpose_w_kernel<<<dim3(16, 64), dim3(32, 8), 0, stream>>>(Wv, Wkvt + 512 * 2048,
                                                               2048, 512);
  transpose_w_kernel<<<dim3(64, 64), dim3(32, 8), 0, stream>>>(Wo, Wot, 2048, 2048);

  gemm_nt<u16><<<dim3(32, 32), 256, 0, stream>>>(xb, Wqt, qraw, 4096, 4096, 2048);
  gemm_nt<u16><<<dim3(8, 32), 256, 0, stream>>>(xb, Wkvt, kvraw, 4096, 1024, 2048);

  // softmax scale folded into Q (Q only feeds scores; gate comes from qraw)
  rmsrope_kernel<<<16384, 256, 0, stream>>>(qraw, qn, Qr, 16, 4096, 256,
                                            0.08838834764831845f);
  rmsrope_kernel<<<4096, 256, 0, stream>>>(kvraw, kn, Kr, 4, 1024, 128, 1.0f);
  transpose_v_kernel<<<dim3(64, 4, 8), dim3(32, 8), 0, stream>>>(kvraw + 512, Vtb,
                                                                 1024);

  attn_kernel<<<dim3(16, 32), 256, 0, stream>>>(Qr, Kr, Vtb, qraw, Ag);
  gemm_nt<float><<<dim3(16, 32), 256, 0, stream>>>(Ag, Wot, out, 4096, 2048, 2048);
}

// Round 5
// 515.705 us; speedup vs baseline: 1.1616x; 1.1616x over previous
//
#include <hip/hip_runtime.h>
#include <hip/hip_bf16.h>

typedef unsigned short u16;
typedef __bf16 bf16x8 __attribute__((ext_vector_type(8)));
typedef float f32x4 __attribute__((ext_vector_type(4)));

#define B_   2
#define S_   2048
#define HID_ 2048
#define H_   16
#define KV_  4
#define D_   128

__device__ __forceinline__ u16 f2b(float f) {
  unsigned u = __float_as_uint(f);
  return (u16)((u + 0x7fffu + ((u >> 16) & 1u)) >> 16);  // RNE
}
__device__ __forceinline__ float b2f(u16 h) {
  return __uint_as_float(((unsigned)h) << 16);
}
__device__ __forceinline__ unsigned pk2(float a, float b) {
  __hip_bfloat162 h = __float22bfloat162_rn(make_float2(a, b));
  unsigned u;
  __builtin_memcpy(&u, &h, 4);
  return u;  // a low 16, b high 16
}
__device__ __forceinline__ void cstore(float* p, float v) { *p = v; }
__device__ __forceinline__ void cstore(u16* p, float v)   { *p = f2b(v); }

// async global->LDS, 16B per lane; LDS dest = wave-uniform base + lane*16
__device__ __forceinline__ void gl_lds16(const u16* g, u16* l) {
  __builtin_amdgcn_global_load_lds(
      (const __attribute__((address_space(1))) unsigned int*)g,
      (__attribute__((address_space(3))) unsigned int*)l, 16, 0, 0);
}

// ---------------------------------------------------------------- cast x -> bf16
__global__ __launch_bounds__(256)
void cast_f2b_kernel(const float* __restrict__ in, u16* __restrict__ out, int n) {
  int i = (blockIdx.x * 256 + threadIdx.x) * 4;
  if (i + 3 < n) {
    float4 v = *(const float4*)(in + i);
    uint2 r = make_uint2(pk2(v.x, v.y), pk2(v.z, v.w));
    *(uint2*)(out + i) = r;
  }
}

// ------------------------------------------- W (R x C) fp32 -> Wt (C x R) bf16
__global__ __launch_bounds__(256)
void transpose_w_kernel(const float* __restrict__ in, u16* __restrict__ out,
                        int R, int Cc) {
  __shared__ u16 t[32][33];
  const int tx = threadIdx.x, ty = threadIdx.y;
  const int c0 = blockIdx.x * 32, r0 = blockIdx.y * 32;
#pragma unroll
  for (int i = 0; i < 4; i++)
    t[ty + i * 8][tx] = f2b(in[(size_t)(r0 + ty + i * 8) * Cc + c0 + tx]);
  __syncthreads();
#pragma unroll
  for (int i = 0; i < 4; i++)
    out[(size_t)(c0 + ty + i * 8) * R + r0 + tx] = t[tx][ty + i * 8];
}

// ------------------- v slice of kvraw (tok, TS) -> Vt (B,KV,D,S) bf16
__global__ __launch_bounds__(256)
void transpose_v_kernel(const u16* __restrict__ in, u16* __restrict__ out,
                        int tokstride) {
  __shared__ u16 t[32][33];
  const int tx = threadIdx.x, ty = threadIdx.y;
  const int s0 = blockIdx.x * 32, d0 = blockIdx.y * 32;
  const int z = blockIdx.z, b = z >> 2, kv = z & 3;
#pragma unroll
  for (int i = 0; i < 4; i++)
    t[ty + i * 8][tx] =
        in[(size_t)(b * S_ + s0 + ty + i * 8) * tokstride + kv * D_ + d0 + tx];
  __syncthreads();
#pragma unroll
  for (int i = 0; i < 4; i++)
    out[((size_t)(b * KV_ + kv) * D_ + d0 + ty + i * 8) * S_ + s0 + tx] =
        t[tx][ty + i * 8];
}

// --------------------------------- NT GEMM: A (M,K) bf16, Bt (N,K) bf16, C (M,N)
// m97 structure: 128x128 tile, BK=32, global_load_lds width=16, unpadded LDS.
template <typename CT>
__global__ __launch_bounds__(256)
void gemm_nt(const u16* __restrict__ A, const u16* __restrict__ Bt,
             CT* __restrict__ C, int Md, int Nd, int Kd) {
  __shared__ u16 As[128 * 32];
  __shared__ u16 Bs[128 * 32];
  const int tid = threadIdx.x;
  const int lane = tid & 63;
  const int wave = tid >> 6;
  const int wm = wave >> 1, wn = wave & 1;
  const int li = lane & 15, quad = lane >> 4;
  const int m0 = blockIdx.y * 128;
  const int n0 = blockIdx.x * 128;

  f32x4 acc[4][4];
#pragma unroll
  for (int i = 0; i < 4; i++)
#pragma unroll
    for (int j = 0; j < 4; j++) acc[i][j] = (f32x4){0.f, 0.f, 0.f, 0.f};

  const int srow = wave * 32 + (lane >> 2);
  const int scol = (lane & 3) * 8;
  const u16* Ag0 = A + (size_t)(m0 + srow) * Kd + scol;
  const u16* Ag1 = Ag0 + (size_t)16 * Kd;
  const u16* Bg0 = Bt + (size_t)(n0 + srow) * Kd + scol;
  const u16* Bg1 = Bg0 + (size_t)16 * Kd;
  u16* Al0 = &As[(wave * 32) * 32];
  u16* Al1 = &As[(wave * 32 + 16) * 32];
  u16* Bl0 = &Bs[(wave * 32) * 32];
  u16* Bl1 = &Bs[(wave * 32 + 16) * 32];

  for (int k0 = 0; k0 < Kd; k0 += 32) {
    __syncthreads();
    gl_lds16(Ag0 + k0, Al0);
    gl_lds16(Ag1 + k0, Al1);
    gl_lds16(Bg0 + k0, Bl0);
    gl_lds16(Bg1 + k0, Bl1);
    __syncthreads();
    bf16x8 af[4], bfr[4];
#pragma unroll
    for (int mt = 0; mt < 4; mt++)
      af[mt] = *(const bf16x8*)&As[(wm * 64 + mt * 16 + li) * 32 + quad * 8];
#pragma unroll
    for (int nt = 0; nt < 4; nt++)
      bfr[nt] = *(const bf16x8*)&Bs[(wn * 64 + nt * 16 + li) * 32 + quad * 8];
#pragma unroll
    for (int mt = 0; mt < 4; mt++)
#pragma unroll
      for (int nt = 0; nt < 4; nt++)
        acc[mt][nt] = __builtin_amdgcn_mfma_f32_16x16x32_bf16(
            af[mt], bfr[nt], acc[mt][nt], 0, 0, 0);
  }
#pragma unroll
  for (int mt = 0; mt < 4; mt++) {
    const int row = m0 + wm * 64 + mt * 16 + quad * 4;
#pragma unroll
    for (int nt = 0; nt < 4; nt++) {
      const int col = n0 + wn * 64 + nt * 16 + li;
#pragma unroll
      for (int r = 0; r < 4; r++)
        cstore(&C[(size_t)(row + r) * Nd + col], acc[mt][nt][r]);
    }
  }
}

// ------------------------ fused RMSNorm (w+1) + RoPE (+ optional score scale)
__global__ __launch_bounds__(256)
void rmsrope_kernel(const u16* __restrict__ in, const float* __restrict__ w,
                    u16* __restrict__ out, int n_heads, int tok_stride,
                    int head_stride, float scale) {
  const int warp = (blockIdx.x << 2) + (threadIdx.x >> 6);
  const int lane = threadIdx.x & 63;
  const int h = warp % n_heads;
  const int tok = warp / n_heads;
  const int s = tok & (S_ - 1);
  const int b = tok >> 11;
  const u16* src = in + (size_t)tok * tok_stride + (size_t)h * head_stride;
  float x1 = b2f(src[lane]);
  float x2 = b2f(src[lane + 64]);
  float ss = x1 * x1 + x2 * x2;
#pragma unroll
  for (int off = 1; off < 64; off <<= 1) ss += __shfl_xor(ss, off);
  const float inv = rsqrtf(ss * (1.0f / 128.0f) + 1e-6f) * scale;
  x1 *= inv * (w[lane] + 1.0f);
  x2 *= inv * (w[lane + 64] + 1.0f);
  const float invf = exp2f((float)lane * (-19.931568569324174f / 64.0f));
  const float ang = (float)s * invf;
  float sn, c;
  sincosf(ang, &sn, &c);
  const size_t ob = (((size_t)b * n_heads + h) * S_ + s) * D_;
  out[ob + lane]      = f2b(x1 * c - x2 * sn);
  out[ob + lane + 64] = f2b(x2 * c + x1 * sn);
}

// --------------------------- flash attention: wave-autonomous, no barriers.
// One wave (64-thr block) per 32-row q-strip. S^T = K·Q^T, O^T = V^T·P^T.
// K and V^T fragments loaded straight global->VGPR (A-operand layout matches
// row-major K / V^T). P C->A transform via 2.5KB wave-private LDS (lgkm only).
// Decode spreads t stride-8 across the blocks a CU receives (anti-aliasing:
// blocks c, c+256, ... would otherwise all get the same strip length).
__global__ __launch_bounds__(64, 2)
void attn_kernel(const u16* __restrict__ Q, const u16* __restrict__ Kr,
                 const u16* __restrict__ Vt, const u16* __restrict__ qraw,
                 u16* __restrict__ Ag) {
  __shared__ u16 Pscr[32 * 40];  // wave-private P scratch (stride 40 elems)

  const int lane = threadIdx.x;
  const int li = lane & 15, quad = lane >> 4;
  const int bx = blockIdx.x, by = blockIdx.y;
  const int bh = bx & 31;
  const int t = (by << 1) | (bx >> 5);  // strip id 0..63
  const int b = bh >> 4, h = bh & 15, kv = h >> 2;
  const int rs = t * 32;  // strip q-row base

  const u16* Qb = Q + ((size_t)bh * S_ + rs) * D_;
  const u16* Kb = Kr + ((size_t)b * KV_ + kv) * S_ * D_;
  const u16* Vb = Vt + ((size_t)b * KV_ + kv) * D_ * S_;

  bf16x8 qf[2][4];  // B-operand of Q^T
#pragma unroll
  for (int n = 0; n < 2; n++)
#pragma unroll
    for (int dc = 0; dc < 4; dc++)
      qf[n][dc] =
          *(const bf16x8*)(Qb + (size_t)(n * 16 + li) * D_ + dc * 32 + quad * 8);

  float m_s[2] = {-1e30f, -1e30f}, l_s[2] = {0.f, 0.f};
  f32x4 oacc[2][8];
#pragma unroll
  for (int n = 0; n < 2; n++)
#pragma unroll
    for (int mt = 0; mt < 8; mt++) oacc[n][mt] = (f32x4){0.f, 0.f, 0.f, 0.f};

  for (int jt = 0; jt <= t; jt++) {
    const int j0 = jt * 32;
    // K fragments: A[m=key16][k=d32], straight from row-major K
    bf16x8 kf[2][4];
#pragma unroll
    for (int mt = 0; mt < 2; mt++)
#pragma unroll
      for (int dc = 0; dc < 4; dc++)
        kf[mt][dc] = *(const bf16x8*)(Kb + (size_t)(j0 + mt * 16 + li) * D_ +
                                      dc * 32 + quad * 8);
    f32x4 sacc[2][2];
#pragma unroll
    for (int n = 0; n < 2; n++)
#pragma unroll
      for (int mt = 0; mt < 2; mt++) sacc[n][mt] = (f32x4){0.f, 0.f, 0.f, 0.f};
#pragma unroll
    for (int dc = 0; dc < 4; dc++)
#pragma unroll
      for (int mt = 0; mt < 2; mt++) {
        sacc[0][mt] = __builtin_amdgcn_mfma_f32_16x16x32_bf16(
            kf[mt][dc], qf[0][dc], sacc[0][mt], 0, 0, 0);
        sacc[1][mt] = __builtin_amdgcn_mfma_f32_16x16x32_bf16(
            kf[mt][dc], qf[1][dc], sacc[1][mt], 0, 0, 0);
      }
    // V^T fragments issued early (latency hidden under softmax)
    bf16x8 vf[8];
#pragma unroll
    for (int mt = 0; mt < 8; mt++)
      vf[mt] = *(const bf16x8*)(Vb + (size_t)(mt * 16 + li) * S_ + j0 + quad * 8);

    if (jt == t) {  // diagonal tile causal mask
#pragma unroll
      for (int n = 0; n < 2; n++)
#pragma unroll
        for (int mt = 0; mt < 2; mt++)
#pragma unroll
          for (int r = 0; r < 4; r++)
            if (mt * 16 + quad * 4 + r > n * 16 + li) sacc[n][mt][r] = -1e30f;
    }
    // online softmax per n-tile (stats across quads: 2 shuffles)
    float alpha2[2];
#pragma unroll
    for (int n = 0; n < 2; n++) {
      float mx = -1e30f;
#pragma unroll
      for (int mt = 0; mt < 2; mt++)
#pragma unroll
        for (int r = 0; r < 4; r++) mx = fmaxf(mx, sacc[n][mt][r]);
      mx = fmaxf(mx, __shfl_xor(mx, 16));
      mx = fmaxf(mx, __shfl_xor(mx, 32));
      const float mn = fmaxf(m_s[n], mx);
      alpha2[n] = __expf(m_s[n] - mn);
      m_s[n] = mn;
      float rsum = 0.f;
#pragma unroll
      for (int mt = 0; mt < 2; mt++)
#pragma unroll
        for (int r = 0; r < 4; r++) {
          float p = __expf(sacc[n][mt][r] - mn);
          sacc[n][mt][r] = p;
          rsum += p;
        }
      rsum += __shfl_xor(rsum, 16);
      rsum += __shfl_xor(rsum, 32);
      l_s[n] = l_s[n] * alpha2[n] + rsum;
      // P (C-layout) -> LDS rows [q][k]
#pragma unroll
      for (int mt = 0; mt < 2; mt++) {
        uint2 w2;
        w2.x = pk2(sacc[n][mt][0], sacc[n][mt][1]);
        w2.y = pk2(sacc[n][mt][2], sacc[n][mt][3]);
        *(uint2*)&Pscr[(n * 16 + li) * 40 + mt * 16 + quad * 4] = w2;
      }
    }
    // rescale O while the LDS writes land (skip when no max moved)
    if (__any((alpha2[0] < 1.f) || (alpha2[1] < 1.f))) {
#pragma unroll
      for (int n = 0; n < 2; n++)
#pragma unroll
        for (int mt = 0; mt < 8; mt++) {
          oacc[n][mt][0] *= alpha2[n];
          oacc[n][mt][1] *= alpha2[n];
          oacc[n][mt][2] *= alpha2[n];
          oacc[n][mt][3] *= alpha2[n];
        }
    }
    asm volatile("s_waitcnt lgkmcnt(0)" ::: "memory");  // wave-private, no barrier
    bf16x8 pf[2];
    pf[0] = *(const bf16x8*)&Pscr[li * 40 + quad * 8];
    pf[1] = *(const bf16x8*)&Pscr[(16 + li) * 40 + quad * 8];
#pragma unroll
    for (int mt = 0; mt < 8; mt++) {
      oacc[0][mt] = __builtin_amdgcn_mfma_f32_16x16x32_bf16(vf[mt], pf[0],
                                                            oacc[0][mt], 0, 0, 0);
      oacc[1][mt] = __builtin_amdgcn_mfma_f32_16x16x32_bf16(vf[mt], pf[1],
                                                            oacc[1][mt], 0, 0, 0);
    }
  }

  // epilogue: normalize, sigmoid-gate (from qraw), store Ag (tok, H*D)
  const float linv0 = 1.f / l_s[0], linv1 = 1.f / l_s[1];
#pragma unroll
  for (int n = 0; n < 2; n++) {
    const float linv = n ? linv1 : linv0;
    const size_t tok = (size_t)b * S_ + rs + n * 16 + li;
    const u16* gp = qraw + tok * 4096 + h * 256 + 128;
    u16* op = Ag + tok * 2048 + h * 128;
#pragma unroll
    for (int mt = 0; mt < 8; mt++) {
      const int dbase = mt * 16 + quad * 4;
      uint2 gv = *(const uint2*)(gp + dbase);
      float g0 = b2f((u16)(gv.x & 0xffff)), g1 = b2f((u16)(gv.x >> 16));
      float g2 = b2f((u16)(gv.y & 0xffff)), g3 = b2f((u16)(gv.y >> 16));
      float o0 = oacc[n][mt][0] * linv / (1.f + __expf(-g0));
      float o1 = oacc[n][mt][1] * linv / (1.f + __expf(-g1));
      float o2 = oacc[n][mt][2] * linv / (1.f + __expf(-g2));
      float o3 = oacc[n][mt][3] * linv / (1.f + __expf(-g3));
      uint2 w2 = make_uint2(pk2(o0, o1), pk2(o2, o3));
      *(uint2*)(op + dbase) = w2;
    }
  }
}

extern "C" void kernel_launch(void* const* d_in, const int* in_sizes, int n_in,
                              void* d_out, int out_size, void* d_ws,
                              size_t ws_size, hipStream_t stream) {
  const float* x  = (const float*)d_in[0];
  const float* Wq = (const float*)d_in[1];
  const float* Wk = (const float*)d_in[2];
  const float* Wv = (const float*)d_in[3];
  const float* Wo = (const float*)d_in[4];
  const float* qn = (const float*)d_in[5];
  const float* kn = (const float*)d_in[6];
  float* out = (float*)d_out;
  char* ws = (char*)d_ws;

  u16* xb    = (u16*)(ws + 0);          // 16.8 MB  x bf16 (4096x2048)
  u16* Wqt   = (u16*)(ws + 16777216);   // 16.8 MB  Wq^T (4096x2048)
  u16* Wkvt  = (u16*)(ws + 33554432);   //  4.2 MB  [Wk^T; Wv^T] (1024x2048)
  u16* Wot   = (u16*)(ws + 37748736);   //  8.4 MB  Wo^T (2048x2048)
  u16* qraw  = (u16*)(ws + 46137344);   // 33.6 MB  q_raw (4096x4096)
  u16* kvraw = (u16*)(ws + 79691776);   //  8.4 MB  [k|v] (4096x1024)
  u16* Vtb   = (u16*)(ws + 88080384);   //  4.2 MB  V^T (B,KV,D,S)
  u16* Kr    = (u16*)(ws + 92274688);   //  4.2 MB  K roped (B,KV,S,D)
  u16* Ag    = (u16*)(ws + 96468992);   // 16.8 MB  gated attn (4096x2048)
  u16* Qr = xb;  // (B,H,S,D) roped+scaled Q (aliases xb, dead after GEMMs)

  cast_f2b_kernel<<<8192, 256, 0, stream>>>(x, xb, 4096 * 2048);
  transpose_w_kernel<<<dim3(128, 64), dim3(32, 8), 0, stream>>>(Wq, Wqt, 2048, 4096);
  transpose_w_kernel<<<dim3(16, 64), dim3(32, 8), 0, stream>>>(Wk, Wkvt, 2048, 512);
  transpose_w_kernel<<<dim3(16, 64), dim3(32, 8), 0, stream>>>(Wv, Wkvt + 512 * 2048,
                                                               2048, 512);
  transpose_w_kernel<<<dim3(64, 64), dim3(32, 8), 0, stream>>>(Wo, Wot, 2048, 2048);

  gemm_nt<u16><<<dim3(32, 32), 256, 0, stream>>>(xb, Wqt, qraw, 4096, 4096, 2048);
  gemm_nt<u16><<<dim3(8, 32), 256, 0, stream>>>(xb, Wkvt, kvraw, 4096, 1024, 2048);

  // softmax scale folded into Q (Q only feeds scores; gate comes from qraw)
  rmsrope_kernel<<<16384, 256, 0, stream>>>(qraw, qn, Qr, 16, 4096, 256,
                                            0.08838834764831845f);
  rmsrope_kernel<<<4096, 256, 0, stream>>>(kvraw, kn, Kr, 4, 1024, 128, 1.0f);
  transpose_v_kernel<<<dim3(64, 4, 8), dim3(32, 8), 0, stream>>>(kvraw + 512, Vtb,
                                                                 1024);

  attn_kernel<<<dim3(64, 32), 64, 0, stream>>>(Qr, Kr, Vtb, qraw, Ag);
  gemm_nt<float><<<dim3(16, 32), 256, 0, stream>>>(Ag, Wot, out, 4096, 2048, 2048);
}

// Round 6
// 513.213 us; speedup vs baseline: 1.1673x; 1.0049x over previous
//
#include <hip/hip_runtime.h>
#include <hip/hip_bf16.h>

typedef unsigned short u16;
typedef __bf16 bf16x8 __attribute__((ext_vector_type(8)));
typedef float f32x4 __attribute__((ext_vector_type(4)));

#define B_   2
#define S_   2048
#define HID_ 2048
#define H_   16
#define KV_  4
#define D_   128

__device__ __forceinline__ u16 f2b(float f) {
  unsigned u = __float_as_uint(f);
  return (u16)((u + 0x7fffu + ((u >> 16) & 1u)) >> 16);  // RNE
}
__device__ __forceinline__ float b2f(u16 h) {
  return __uint_as_float(((unsigned)h) << 16);
}
__device__ __forceinline__ unsigned pk2(float a, float b) {
  __hip_bfloat162 h = __float22bfloat162_rn(make_float2(a, b));
  unsigned u;
  __builtin_memcpy(&u, &h, 4);
  return u;  // a low 16, b high 16
}
__device__ __forceinline__ void cstore(float* p, float v) { *p = v; }
__device__ __forceinline__ void cstore(u16* p, float v)   { *p = f2b(v); }

// async global->LDS, 16B per lane; LDS dest = wave-uniform base + lane*16
__device__ __forceinline__ void gl_lds16(const u16* g, u16* l) {
  __builtin_amdgcn_global_load_lds(
      (const __attribute__((address_space(1))) unsigned int*)g,
      (__attribute__((address_space(3))) unsigned int*)l, 16, 0, 0);
}

// ---------------------------------------------------------------- cast x -> bf16
__global__ __launch_bounds__(256)
void cast_f2b_kernel(const float* __restrict__ in, u16* __restrict__ out, int n) {
  int i = (blockIdx.x * 256 + threadIdx.x) * 4;
  if (i + 3 < n) {
    float4 v = *(const float4*)(in + i);
    uint2 r = make_uint2(pk2(v.x, v.y), pk2(v.z, v.w));
    *(uint2*)(out + i) = r;
  }
}

// ------------------------------------------- W (R x C) fp32 -> Wt (C x R) bf16
__global__ __launch_bounds__(256)
void transpose_w_kernel(const float* __restrict__ in, u16* __restrict__ out,
                        int R, int Cc) {
  __shared__ u16 t[32][33];
  const int tx = threadIdx.x, ty = threadIdx.y;
  const int c0 = blockIdx.x * 32, r0 = blockIdx.y * 32;
#pragma unroll
  for (int i = 0; i < 4; i++)
    t[ty + i * 8][tx] = f2b(in[(size_t)(r0 + ty + i * 8) * Cc + c0 + tx]);
  __syncthreads();
#pragma unroll
  for (int i = 0; i < 4; i++)
    out[(size_t)(c0 + ty + i * 8) * R + r0 + tx] = t[tx][ty + i * 8];
}

// ------------------- v slice of kvraw (tok, TS) -> Vt (B,KV,D,S) bf16
__global__ __launch_bounds__(256)
void transpose_v_kernel(const u16* __restrict__ in, u16* __restrict__ out,
                        int tokstride) {
  __shared__ u16 t[32][33];
  const int tx = threadIdx.x, ty = threadIdx.y;
  const int s0 = blockIdx.x * 32, d0 = blockIdx.y * 32;
  const int z = blockIdx.z, b = z >> 2, kv = z & 3;
#pragma unroll
  for (int i = 0; i < 4; i++)
    t[ty + i * 8][tx] =
        in[(size_t)(b * S_ + s0 + ty + i * 8) * tokstride + kv * D_ + d0 + tx];
  __syncthreads();
#pragma unroll
  for (int i = 0; i < 4; i++)
    out[((size_t)(b * KV_ + kv) * D_ + d0 + ty + i * 8) * S_ + s0 + tx] =
        t[tx][ty + i * 8];
}

// --------------------------------- NT GEMM: A (M,K) bf16, Bt (N,K) bf16, C (M,N)
// m97 structure: 128x128 tile, BK=32, global_load_lds width=16, unpadded LDS.
template <typename CT>
__global__ __launch_bounds__(256)
void gemm_nt(const u16* __restrict__ A, const u16* __restrict__ Bt,
             CT* __restrict__ C, int Md, int Nd, int Kd) {
  __shared__ u16 As[128 * 32];
  __shared__ u16 Bs[128 * 32];
  const int tid = threadIdx.x;
  const int lane = tid & 63;
  const int wave = tid >> 6;
  const int wm = wave >> 1, wn = wave & 1;
  const int li = lane & 15, quad = lane >> 4;
  const int m0 = blockIdx.y * 128;
  const int n0 = blockIdx.x * 128;

  f32x4 acc[4][4];
#pragma unroll
  for (int i = 0; i < 4; i++)
#pragma unroll
    for (int j = 0; j < 4; j++) acc[i][j] = (f32x4){0.f, 0.f, 0.f, 0.f};

  const int srow = wave * 32 + (lane >> 2);
  const int scol = (lane & 3) * 8;
  const u16* Ag0 = A + (size_t)(m0 + srow) * Kd + scol;
  const u16* Ag1 = Ag0 + (size_t)16 * Kd;
  const u16* Bg0 = Bt + (size_t)(n0 + srow) * Kd + scol;
  const u16* Bg1 = Bg0 + (size_t)16 * Kd;
  u16* Al0 = &As[(wave * 32) * 32];
  u16* Al1 = &As[(wave * 32 + 16) * 32];
  u16* Bl0 = &Bs[(wave * 32) * 32];
  u16* Bl1 = &Bs[(wave * 32 + 16) * 32];

  for (int k0 = 0; k0 < Kd; k0 += 32) {
    __syncthreads();
    gl_lds16(Ag0 + k0, Al0);
    gl_lds16(Ag1 + k0, Al1);
    gl_lds16(Bg0 + k0, Bl0);
    gl_lds16(Bg1 + k0, Bl1);
    __syncthreads();
    bf16x8 af[4], bfr[4];
#pragma unroll
    for (int mt = 0; mt < 4; mt++)
      af[mt] = *(const bf16x8*)&As[(wm * 64 + mt * 16 + li) * 32 + quad * 8];
#pragma unroll
    for (int nt = 0; nt < 4; nt++)
      bfr[nt] = *(const bf16x8*)&Bs[(wn * 64 + nt * 16 + li) * 32 + quad * 8];
#pragma unroll
    for (int mt = 0; mt < 4; mt++)
#pragma unroll
      for (int nt = 0; nt < 4; nt++)
        acc[mt][nt] = __builtin_amdgcn_mfma_f32_16x16x32_bf16(
            af[mt], bfr[nt], acc[mt][nt], 0, 0, 0);
  }
#pragma unroll
  for (int mt = 0; mt < 4; mt++) {
    const int row = m0 + wm * 64 + mt * 16 + quad * 4;
#pragma unroll
    for (int nt = 0; nt < 4; nt++) {
      const int col = n0 + wn * 64 + nt * 16 + li;
#pragma unroll
      for (int r = 0; r < 4; r++)
        cstore(&C[(size_t)(row + r) * Nd + col], acc[mt][nt][r]);
    }
  }
}

// ------------------------ fused RMSNorm (w+1) + RoPE (+ optional score scale)
__global__ __launch_bounds__(256)
void rmsrope_kernel(const u16* __restrict__ in, const float* __restrict__ w,
                    u16* __restrict__ out, int n_heads, int tok_stride,
                    int head_stride, float scale) {
  const int warp = (blockIdx.x << 2) + (threadIdx.x >> 6);
  const int lane = threadIdx.x & 63;
  const int h = warp % n_heads;
  const int tok = warp / n_heads;
  const int s = tok & (S_ - 1);
  const int b = tok >> 11;
  const u16* src = in + (size_t)tok * tok_stride + (size_t)h * head_stride;
  float x1 = b2f(src[lane]);
  float x2 = b2f(src[lane + 64]);
  float ss = x1 * x1 + x2 * x2;
#pragma unroll
  for (int off = 1; off < 64; off <<= 1) ss += __shfl_xor(ss, off);
  const float inv = rsqrtf(ss * (1.0f / 128.0f) + 1e-6f) * scale;
  x1 *= inv * (w[lane] + 1.0f);
  x2 *= inv * (w[lane + 64] + 1.0f);
  const float invf = exp2f((float)lane * (-19.931568569324174f / 64.0f));
  const float ang = (float)s * invf;
  float sn, c;
  sincosf(ang, &sn, &c);
  const size_t ob = (((size_t)b * n_heads + h) * S_ + s) * D_;
  out[ob + lane]      = f2b(x1 * c - x2 * sn);
  out[ob + lane + 64] = f2b(x2 * c + x1 * sn);
}

// --------------------------- flash attention: wave-autonomous, no barriers,
// K VGPR-double-buffered (next tile's K loads fly under current tile's
// MFMA+softmax; V loads fly under softmax). One wave per 32-row q-strip.
__global__ __launch_bounds__(64, 2)
void attn_kernel(const u16* __restrict__ Q, const u16* __restrict__ Kr,
                 const u16* __restrict__ Vt, const u16* __restrict__ qraw,
                 u16* __restrict__ Ag) {
  __shared__ u16 Pscr[32 * 40];  // wave-private P scratch (stride 40 elems)

  const int lane = threadIdx.x;
  const int li = lane & 15, quad = lane >> 4;
  const int bx = blockIdx.x, by = blockIdx.y;
  const int bh = bx & 31;
  const int t = (by << 1) | (bx >> 5);  // strip id 0..63
  const int b = bh >> 4, h = bh & 15, kv = h >> 2;
  const int rs = t * 32;  // strip q-row base

  const u16* Qb = Q + ((size_t)bh * S_ + rs) * D_;
  const u16* Kb = Kr + ((size_t)b * KV_ + kv) * S_ * D_;
  const u16* Vb = Vt + ((size_t)b * KV_ + kv) * D_ * S_;

  bf16x8 qf[2][4];  // B-operand of Q^T
#pragma unroll
  for (int n = 0; n < 2; n++)
#pragma unroll
    for (int dc = 0; dc < 4; dc++)
      qf[n][dc] =
          *(const bf16x8*)(Qb + (size_t)(n * 16 + li) * D_ + dc * 32 + quad * 8);

  float m_s[2] = {-1e30f, -1e30f}, l_s[2] = {0.f, 0.f};
  f32x4 oacc[2][8];
#pragma unroll
  for (int n = 0; n < 2; n++)
#pragma unroll
    for (int mt = 0; mt < 8; mt++) oacc[n][mt] = (f32x4){0.f, 0.f, 0.f, 0.f};

  bf16x8 ka[2][4], kb2[2][4];  // K double buffer

  auto loadK = [&](bf16x8 (&kf)[2][4], int j0) {
#pragma unroll
    for (int mt = 0; mt < 2; mt++)
#pragma unroll
      for (int dc = 0; dc < 4; dc++)
        kf[mt][dc] = *(const bf16x8*)(Kb + (size_t)(j0 + mt * 16 + li) * D_ +
                                      dc * 32 + quad * 8);
  };

  auto step = [&](bf16x8 (&kf)[2][4], bf16x8 (&kn)[2][4], int jt) {
    const int j0 = jt * 32;
    // V loads for this tile (consumed after softmax) — issue first
    bf16x8 vf[8];
#pragma unroll
    for (int mt = 0; mt < 8; mt++)
      vf[mt] = *(const bf16x8*)(Vb + (size_t)(mt * 16 + li) * S_ + j0 + quad * 8);
    // prefetch next tile's K into the other buffer (consumed next iteration)
    if (jt + 1 <= t) loadK(kn, j0 + 32);

    // S^T = K·Q^T on the resident buffer (no vm wait on in-flight loads)
    f32x4 sacc[2][2];
#pragma unroll
    for (int n = 0; n < 2; n++)
#pragma unroll
      for (int mt = 0; mt < 2; mt++) sacc[n][mt] = (f32x4){0.f, 0.f, 0.f, 0.f};
#pragma unroll
    for (int dc = 0; dc < 4; dc++)
#pragma unroll
      for (int mt = 0; mt < 2; mt++) {
        sacc[0][mt] = __builtin_amdgcn_mfma_f32_16x16x32_bf16(
            kf[mt][dc], qf[0][dc], sacc[0][mt], 0, 0, 0);
        sacc[1][mt] = __builtin_amdgcn_mfma_f32_16x16x32_bf16(
            kf[mt][dc], qf[1][dc], sacc[1][mt], 0, 0, 0);
      }

    if (jt == t) {  // diagonal tile causal mask
#pragma unroll
      for (int n = 0; n < 2; n++)
#pragma unroll
        for (int mt = 0; mt < 2; mt++)
#pragma unroll
          for (int r = 0; r < 4; r++)
            if (mt * 16 + quad * 4 + r > n * 16 + li) sacc[n][mt][r] = -1e30f;
    }
    // online softmax per n-tile (stats across quads: 2 shuffles)
    float alpha2[2];
#pragma unroll
    for (int n = 0; n < 2; n++) {
      float mx = -1e30f;
#pragma unroll
      for (int mt = 0; mt < 2; mt++)
#pragma unroll
        for (int r = 0; r < 4; r++) mx = fmaxf(mx, sacc[n][mt][r]);
      mx = fmaxf(mx, __shfl_xor(mx, 16));
      mx = fmaxf(mx, __shfl_xor(mx, 32));
      const float mn = fmaxf(m_s[n], mx);
      alpha2[n] = __expf(m_s[n] - mn);
      m_s[n] = mn;
      float rsum = 0.f;
#pragma unroll
      for (int mt = 0; mt < 2; mt++)
#pragma unroll
        for (int r = 0; r < 4; r++) {
          float p = __expf(sacc[n][mt][r] - mn);
          sacc[n][mt][r] = p;
          rsum += p;
        }
      rsum += __shfl_xor(rsum, 16);
      rsum += __shfl_xor(rsum, 32);
      l_s[n] = l_s[n] * alpha2[n] + rsum;
      // P (C-layout) -> LDS rows [q][k]
#pragma unroll
      for (int mt = 0; mt < 2; mt++) {
        uint2 w2;
        w2.x = pk2(sacc[n][mt][0], sacc[n][mt][1]);
        w2.y = pk2(sacc[n][mt][2], sacc[n][mt][3]);
        *(uint2*)&Pscr[(n * 16 + li) * 40 + mt * 16 + quad * 4] = w2;
      }
    }
    // rescale O while the LDS writes land (skip when no max moved)
    if (__any((alpha2[0] < 1.f) || (alpha2[1] < 1.f))) {
#pragma unroll
      for (int n = 0; n < 2; n++)
#pragma unroll
        for (int mt = 0; mt < 8; mt++) {
          oacc[n][mt][0] *= alpha2[n];
          oacc[n][mt][1] *= alpha2[n];
          oacc[n][mt][2] *= alpha2[n];
          oacc[n][mt][3] *= alpha2[n];
        }
    }
    asm volatile("s_waitcnt lgkmcnt(0)" ::: "memory");  // wave-private, no barrier
    bf16x8 pf[2];
    pf[0] = *(const bf16x8*)&Pscr[li * 40 + quad * 8];
    pf[1] = *(const bf16x8*)&Pscr[(16 + li) * 40 + quad * 8];
#pragma unroll
    for (int mt = 0; mt < 8; mt++) {
      oacc[0][mt] = __builtin_amdgcn_mfma_f32_16x16x32_bf16(vf[mt], pf[0],
                                                            oacc[0][mt], 0, 0, 0);
      oacc[1][mt] = __builtin_amdgcn_mfma_f32_16x16x32_bf16(vf[mt], pf[1],
                                                            oacc[1][mt], 0, 0, 0);
    }
  };

  loadK(ka, 0);
  for (int jt = 0; jt <= t; jt += 2) {
    step(ka, kb2, jt);
    if (jt + 1 <= t) step(kb2, ka, jt + 1);
  }

  // epilogue: normalize, sigmoid-gate (from qraw), store Ag (tok, H*D)
  const float linv0 = 1.f / l_s[0], linv1 = 1.f / l_s[1];
#pragma unroll
  for (int n = 0; n < 2; n++) {
    const float linv = n ? linv1 : linv0;
    const size_t tok = (size_t)b * S_ + rs + n * 16 + li;
    const u16* gp = qraw + tok * 4096 + h * 256 + 128;
    u16* op = Ag + tok * 2048 + h * 128;
#pragma unroll
    for (int mt = 0; mt < 8; mt++) {
      const int dbase = mt * 16 + quad * 4;
      uint2 gv = *(const uint2*)(gp + dbase);
      float g0 = b2f((u16)(gv.x & 0xffff)), g1 = b2f((u16)(gv.x >> 16));
      float g2 = b2f((u16)(gv.y & 0xffff)), g3 = b2f((u16)(gv.y >> 16));
      float o0 = oacc[n][mt][0] * linv / (1.f + __expf(-g0));
      float o1 = oacc[n][mt][1] * linv / (1.f + __expf(-g1));
      float o2 = oacc[n][mt][2] * linv / (1.f + __expf(-g2));
      float o3 = oacc[n][mt][3] * linv / (1.f + __expf(-g3));
      uint2 w2 = make_uint2(pk2(o0, o1), pk2(o2, o3));
      *(uint2*)(op + dbase) = w2;
    }
  }
}

extern "C" void kernel_launch(void* const* d_in, const int* in_sizes, int n_in,
                              void* d_out, int out_size, void* d_ws,
                              size_t ws_size, hipStream_t stream) {
  const float* x  = (const float*)d_in[0];
  const float* Wq = (const float*)d_in[1];
  const float* Wk = (const float*)d_in[2];
  const float* Wv = (const float*)d_in[3];
  const float* Wo = (const float*)d_in[4];
  const float* qn = (const float*)d_in[5];
  const float* kn = (const float*)d_in[6];
  float* out = (float*)d_out;
  char* ws = (char*)d_ws;

  u16* xb    = (u16*)(ws + 0);          // 16.8 MB  x bf16 (4096x2048)
  u16* Wqt   = (u16*)(ws + 16777216);   // 16.8 MB  Wq^T (4096x2048)
  u16* Wkvt  = (u16*)(ws + 33554432);   //  4.2 MB  [Wk^T; Wv^T] (1024x2048)
  u16* Wot   = (u16*)(ws + 37748736);   //  8.4 MB  Wo^T (2048x2048)
  u16* qraw  = (u16*)(ws + 46137344);   // 33.6 MB  q_raw (4096x4096)
  u16* kvraw = (u16*)(ws + 79691776);   //  8.4 MB  [k|v] (4096x1024)
  u16* Vtb   = (u16*)(ws + 88080384);   //  4.2 MB  V^T (B,KV,D,S)
  u16* Kr    = (u16*)(ws + 92274688);   //  4.2 MB  K roped (B,KV,S,D)
  u16* Ag    = (u16*)(ws + 96468992);   // 16.8 MB  gated attn (4096x2048)
  u16* Qr = xb;  // (B,H,S,D) roped+scaled Q (aliases xb, dead after GEMMs)

  cast_f2b_kernel<<<8192, 256, 0, stream>>>(x, xb, 4096 * 2048);
  transpose_w_kernel<<<dim3(128, 64), dim3(32, 8), 0, stream>>>(Wq, Wqt, 2048, 4096);
  transpose_w_kernel<<<dim3(16, 64), dim3(32, 8), 0, stream>>>(Wk, Wkvt, 2048, 512);
  transpose_w_kernel<<<dim3(16, 64), dim3(32, 8), 0, stream>>>(Wv, Wkvt + 512 * 2048,
                                                               2048, 512);
  transpose_w_kernel<<<dim3(64, 64), dim3(32, 8), 0, stream>>>(Wo, Wot, 2048, 2048);

  gemm_nt<u16><<<dim3(32, 32), 256, 0, stream>>>(xb, Wqt, qraw, 4096, 4096, 2048);
  gemm_nt<u16><<<dim3(8, 32), 256, 0, stream>>>(xb, Wkvt, kvraw, 4096, 1024, 2048);

  // softmax scale folded into Q (Q only feeds scores; gate comes from qraw)
  rmsrope_kernel<<<16384, 256, 0, stream>>>(qraw, qn, Qr, 16, 4096, 256,
                                            0.08838834764831845f);
  rmsrope_kernel<<<4096, 256, 0, stream>>>(kvraw, kn, Kr, 4, 1024, 128, 1.0f);
  transpose_v_kernel<<<dim3(64, 4, 8), dim3(32, 8), 0, stream>>>(kvraw + 512, Vtb,
                                                                 1024);

  attn_kernel<<<dim3(64, 32), 64, 0, stream>>>(Qr, Kr, Vtb, qraw, Ag);
  gemm_nt<float><<<dim3(16, 32), 256, 0, stream>>>(Ag, Wot, out, 4096, 2048, 2048);
}